// Round 14
// baseline (1837.171 us; speedup 1.0000x reference)
//
#include <hip/hip_runtime.h>
#include <hip/hip_bf16.h>

typedef __bf16 bf16x8 __attribute__((ext_vector_type(8)));
typedef _Float16 f16x8 __attribute__((ext_vector_type(8)));
typedef float f32x4 __attribute__((ext_vector_type(4)));

__device__ __forceinline__ unsigned short f2bf(float f) {
    unsigned int u = __builtin_bit_cast(unsigned int, f);
    u += 0x7FFFu + ((u >> 16) & 1u);
    return (unsigned short)(u >> 16);
}
__device__ __forceinline__ float bf2f(unsigned short s) {
    unsigned int u = ((unsigned int)s) << 16;
    return __builtin_bit_cast(float, u);
}

// Coherent (L1/L2-bypass, L3-served) accesses.
__device__ __forceinline__ void ldg_c(uint4& d, const void* p) {
    asm volatile("global_load_dwordx4 %0, %1, off sc0 sc1" : "=v"(d) : "v"(p));
}
__device__ __forceinline__ void stg_c32(void* p, unsigned v) {
    asm volatile("global_store_dword %0, %1, off sc0 sc1" :: "v"(p), "v"(v) : "memory");
}
__device__ __forceinline__ void vm_drain() {
    asm volatile("s_waitcnt vmcnt(0)" ::: "memory");
    __builtin_amdgcn_sched_barrier(0);
}
__device__ __forceinline__ void lds_fence() {
    asm volatile("s_waitcnt lgkmcnt(0)" ::: "memory");
    __builtin_amdgcn_sched_barrier(0);
}

// Wave-parallel flag wait: 64 lanes each watch one CU's flag word.
__device__ __forceinline__ void wait_flags(const unsigned* f, unsigned tgt) {
    int lane = threadIdx.x & 63;
    for (;;) {
        unsigned v = __hip_atomic_load(f + lane, __ATOMIC_RELAXED, __HIP_MEMORY_SCOPE_AGENT);
        if (__all((int)(v >= tgt))) break;
        __builtin_amdgcn_s_sleep(1);
    }
}

// ---------------- prep: x -> split bf16 hi/lo in MFMA B-fragment layout ----------------
__global__ void prep_x(const float* __restrict__ x,
                       unsigned short* __restrict__ xh,
                       unsigned short* __restrict__ xl) {
    int g = blockIdx.x * 256 + threadIdx.x;   // 1,638,400 frags
    if (g >= 1638400) return;
    int lane = g & 63;
    int kc   = (g >> 6) & 15;
    int nt   = (g >> 10) & 7;
    int t    = g >> 13;
    int batch = nt * 16 + (lane & 15);
    int k = kc * 32 + (lane >> 4) * 8;
    const float* s = x + ((size_t)batch * 200 + t) * 512 + k;
    float4 v0 = *(const float4*)s;
    float4 v1 = *(const float4*)(s + 4);
    float vv[8] = {v0.x, v0.y, v0.z, v0.w, v1.x, v1.y, v1.z, v1.w};
    unsigned int ph[4], pl[4];
    #pragma unroll
    for (int j = 0; j < 4; ++j) {
        float a = vv[2*j], b = vv[2*j+1];
        unsigned short ha = f2bf(a), hb = f2bf(b);
        unsigned short la = f2bf(a - bf2f(ha)), lb = f2bf(b - bf2f(hb));
        ph[j] = (unsigned)ha | ((unsigned)hb << 16);
        pl[j] = (unsigned)la | ((unsigned)lb << 16);
    }
    ((uint4*)xh)[g] = make_uint4(ph[0], ph[1], ph[2], ph[3]);
    ((uint4*)xl)[g] = make_uint4(pl[0], pl[1], pl[2], pl[3]);
}

// ---------------- prep: weights -> per-CU LDS image blocks ----------------
__global__ void prep_w(const float* __restrict__ W,     // [2][2048][512] f32
                       unsigned short* __restrict__ wprep,
                       int dir, int isHH) {
    int g = blockIdx.x * 256 + threadIdx.x;   // 262,144
    if (g >= 262144) return;
    int lane = g & 63;
    int kc   = (g >> 6) & 15;
    int mt   = (g >> 10) & 1;
    int cu   = (g >> 11) & 63;
    int l    = g >> 17;
    int r = lane & 15;
    int grow = (2 * mt + (r >> 3)) * 512 + cu * 8 + (r & 7);
    int k = kc * 32 + (lane >> 4) * 8;
    const float* s = W + ((size_t)l * 2048 + grow) * 512 + k;
    float4 v0 = *(const float4*)s;
    float4 v1 = *(const float4*)(s + 4);
    float vv[8] = {v0.x, v0.y, v0.z, v0.w, v1.x, v1.y, v1.z, v1.w};
    bool f16fmt = isHH || (l == 1);
    unsigned int ph[4], pl[4];
    #pragma unroll
    for (int j = 0; j < 4; ++j) {
        float a = vv[2*j], b = vv[2*j+1];
        unsigned short ha, hb, la, lb;
        if (f16fmt) {
            _Float16 fa = (_Float16)a, fb = (_Float16)b;
            _Float16 ra = (_Float16)(a - (float)fa), rb = (_Float16)(b - (float)fb);
            ha = __builtin_bit_cast(unsigned short, fa);
            hb = __builtin_bit_cast(unsigned short, fb);
            la = __builtin_bit_cast(unsigned short, ra);
            lb = __builtin_bit_cast(unsigned short, rb);
        } else {
            ha = f2bf(a); hb = f2bf(b);
            la = f2bf(a - bf2f(ha)); lb = f2bf(b - bf2f(hb));
        }
        ph[j] = (unsigned)ha | ((unsigned)hb << 16);
        pl[j] = (unsigned)la | ((unsigned)lb << 16);
    }
    size_t blk = ((size_t)(dir * 2 + l) * 64 + cu) * 8192;
    size_t fH = blk + (size_t)((isHH * 2 + 0) * 2048 + mt * 1024 + kc * 64 + lane);
    size_t fL = blk + (size_t)((isHH * 2 + 1) * 2048 + mt * 1024 + kc * 64 + lane);
    ((uint4*)wprep)[fH] = make_uint4(ph[0], ph[1], ph[2], ph[3]);
    ((uint4*)wprep)[fL] = make_uint4(pl[0], pl[1], pl[2], pl[3]);
}

__global__ void bsum_k(const float* __restrict__ bih_f, const float* __restrict__ bhh_f,
                       const float* __restrict__ bih_b, const float* __restrict__ bhh_b,
                       float* __restrict__ bsum) {
    int i = blockIdx.x * 256 + threadIdx.x;   // 8192 = [dir][l][2048]
    if (i < 8192) {
        int dir = i >> 12, rem = i & 4095;
        const float* bi = dir ? bih_b : bih_f;
        const float* bh = dir ? bhh_b : bhh_f;
        bsum[i] = bi[rem] + bh[rem];
    }
}

__global__ void reset_k(uint4* __restrict__ p, int n) {
    int g = blockIdx.x * 256 + threadIdx.x;
    if (g < n) p[g] = make_uint4(0, 0, 0, 0);
}

// ---------------- persistent LSTM --------------------------------------------------
// DEEP=0: r13 structure verbatim (quad-buffered h, sc0/sc1 loads).
// DEEP=1: h stored as a 200-deep per-(slot,dir) sequence — every address written
// exactly once (write-through), so consumer loads can be NORMAL CACHED loads:
// first toucher on an XCD fills L2 from L3, the other 31 CUs hit L2. h_{-1}=0 is
// handled by skipping the hh term at t==0 (no init). Weight staging uses sc0/sc1
// loads (hseq aliases wprep; no wprep address may enter L2) + a stage barrier.
template<int DEEP>
__global__ void __launch_bounds__(512)
lstm_persist(const unsigned short* __restrict__ xh,
             const unsigned short* __restrict__ xl,
             const unsigned short* __restrict__ wprep,
             const float*          __restrict__ bsum,
             unsigned short*       __restrict__ hbuf,   // DEEP0: quad-buf; DEEP1: hseq
             const int*            __restrict__ lens,
             float*                __restrict__ dout,   // [128][200][1024]
             unsigned*             __restrict__ flagv,  // [unit4][cu64]
             unsigned*             __restrict__ sflg)   // stage flags (DEEP1)
{
    extern __shared__ char smem[];
    float* wexch  = (float*)(smem + 131072);                  // [ng8][32][17]
    float* cst    = (float*)(smem + 131072 + 17408);          // [u8][132]
    float* bias_l = (float*)(smem + 131072 + 17408 + 4224);   // [32]

    const int bid  = blockIdx.x;
    const int xcd  = bid & 7;
    const int unit = xcd >> 1;                        // slot-major: slot*2 + dir
    const int slot = unit >> 1, dir = unit & 1;
    const int cu8  = ((xcd & 1) << 5) | (bid >> 3);   // 0..63
    const int hj0  = cu8 * 8;
    const int tid  = threadIdx.x;
    const int lane = tid & 63, ng = tid >> 6;         // wave = batch group
    const int l15  = lane & 15, kg = lane >> 4;
    const int wsel = dir * 2 + slot;                  // dir-major, matches prep_w/bsum

    const int sib = slot ? dir : (2 + dir);           // other slot, same dir
    unsigned* own_f = flagv + unit * 64;
    unsigned* sib_f = flagv + sib * 64;

    // DEEP1 stream bases (each stream = 200 x 65536 fp16 = 13,107,200 shorts)
    unsigned short* own_stream = hbuf + (size_t)unit * 13107200;
    const unsigned short* x_stream = hbuf + (size_t)dir * 13107200;  // slot0 of same dir

    // ---- stage weights into LDS (one-time) ----
    if constexpr (DEEP) {
        const unsigned short* src = wprep + (size_t)(wsel * 64 + cu8) * 65536;
        uint4 v[16];
        #pragma unroll
        for (int i = 0; i < 16; ++i)
            ldg_c(v[i], src + (size_t)(tid + i * 512) * 8);
        vm_drain();
        uint4* dst = (uint4*)smem;
        #pragma unroll
        for (int i = 0; i < 16; ++i) dst[tid + i * 512] = v[i];
    } else {
        const uint4* src = (const uint4*)wprep + ((size_t)(wsel * 64 + cu8) * 8192);
        uint4* dst = (uint4*)smem;
        #pragma unroll
        for (int i = 0; i < 16; ++i) dst[tid + i * 512] = src[tid + i * 512];
    }
    for (int i = tid; i < 8 * 132; i += 512) cst[i] = 0.f;
    if (tid < 32) bias_l[tid] = bsum[wsel * 2048 + (tid >> 3) * 512 + hj0 + (tid & 7)];
    __syncthreads();

    if constexpr (DEEP) {
        // stage barrier: slot0 must not overwrite wprep (aliased) until all staged
        if (tid == 0)
            __hip_atomic_store(sflg + unit * 64 + cu8, 1u,
                               __ATOMIC_RELAXED, __HIP_MEMORY_SCOPE_AGENT);
        if (slot == 0 && ng < 4) wait_flags(sflg + ng * 64, 1u);
        __syncthreads();
    }

    // ---- loop invariants ----
    const int lenv = lens[ng * 16 + l15];
    const int gb   = ng * 16 + l15;
    const int u0   = kg * 2;
    const size_t lofs = (size_t)lane * 8;
    const size_t hoff = ((size_t)(ng * 16 + (cu8 >> 2)) * 64 + (cu8 & 3) * 16 + l15) * 8 + u0;
    float* wex = wexch + ng * 32 * 17;

    for (int tau = 0; tau <= 200; ++tau) {
        const int t = slot ? (tau - 1) : tau;
        const bool active = (t >= 0 && t <= 199);
        int t_eff = 0, p_w = 0, p_r = 0;
        if (active) { t_eff = dir ? (199 - t) : t; p_w = t & 3; p_r = (t + 3) & 3; }

        f32x4 acc0 = {0.f, 0.f, 0.f, 0.f};
        f32x4 acc1 = {0.f, 0.f, 0.f, 0.f};

        // ---- Phase 1 (slot0 only): ih * x_t (split-bf16) ----
        if (slot == 0 && active) {
            const unsigned short* XH = xh + (size_t)t_eff * 65536;
            const unsigned short* XL = xl + (size_t)t_eff * 65536;
            #pragma unroll
            for (int kc = 0; kc < 16; ++kc) {
                size_t bo = (size_t)ng * 8192 + (size_t)kc * 512 + lofs;
                bf16x8 bxh = *(const bf16x8*)(XH + bo);
                bf16x8 bxl = *(const bf16x8*)(XL + bo);
                const char* ab = smem + kc * 1024 + lane * 16;
                bf16x8 aih0 = *(const bf16x8*)(ab);
                bf16x8 ail0 = *(const bf16x8*)(ab + 32768);
                bf16x8 aih1 = *(const bf16x8*)(ab + 16384);
                bf16x8 ail1 = *(const bf16x8*)(ab + 16384 + 32768);
                acc0 = __builtin_amdgcn_mfma_f32_16x16x32_bf16(aih0, bxh, acc0, 0, 0, 0);
                acc0 = __builtin_amdgcn_mfma_f32_16x16x32_bf16(aih0, bxl, acc0, 0, 0, 0);
                acc0 = __builtin_amdgcn_mfma_f32_16x16x32_bf16(ail0, bxh, acc0, 0, 0, 0);
                acc1 = __builtin_amdgcn_mfma_f32_16x16x32_bf16(aih1, bxh, acc1, 0, 0, 0);
                acc1 = __builtin_amdgcn_mfma_f32_16x16x32_bf16(aih1, bxl, acc1, 0, 0, 0);
                acc1 = __builtin_amdgcn_mfma_f32_16x16x32_bf16(ail1, bxh, acc1, 0, 0, 0);
            }
        }

        // ---- wait for dependencies ----
        {
            unsigned tgt = (unsigned)tau;
            if (ng == 0) wait_flags(own_f, tgt);
            if (slot == 1) { if (ng == 1) wait_flags(sib_f, tgt); }
            else if constexpr (!DEEP) {
                if (ng == 1 && tau >= 3) wait_flags(sib_f, tgt - 2);   // WAR (quad-buf only)
            }
        }
        __syncthreads();

        if (active) {
            const unsigned short* HH;
            if constexpr (DEEP)
                HH = own_stream + (size_t)(t > 0 ? t - 1 : 0) * 65536;
            else
                HH = hbuf + ((size_t)((slot * 4 + p_r) * 2 + dir) << 16);
            const bool do_hh = DEEP ? (t > 0) : true;

            // ---- Phase 2: recurrent terms via fp16 h ----
            if (slot == 0) {
                if (do_hh) {
                    uint4 vh[16];
                    if constexpr (DEEP) {
                        #pragma unroll
                        for (int kc = 0; kc < 16; ++kc)
                            vh[kc] = *(const uint4*)(HH + (size_t)ng * 8192 + (size_t)kc * 512 + lofs);
                    } else {
                        #pragma unroll
                        for (int kc = 0; kc < 16; ++kc)
                            ldg_c(vh[kc], HH + (size_t)ng * 8192 + (size_t)kc * 512 + lofs);
                        vm_drain();
                    }
                    #pragma unroll
                    for (int kc = 0; kc < 16; ++kc) {
                        f16x8 bh = __builtin_bit_cast(f16x8, vh[kc]);
                        const char* ab = smem + kc * 1024 + lane * 16;
                        f16x8 ahh0 = *(const f16x8*)(ab + 65536);
                        f16x8 ahl0 = *(const f16x8*)(ab + 98304);
                        f16x8 ahh1 = *(const f16x8*)(ab + 16384 + 65536);
                        f16x8 ahl1 = *(const f16x8*)(ab + 16384 + 98304);
                        acc0 = __builtin_amdgcn_mfma_f32_16x16x32_f16(ahh0, bh, acc0, 0, 0, 0);
                        acc0 = __builtin_amdgcn_mfma_f32_16x16x32_f16(ahl0, bh, acc0, 0, 0, 0);
                        acc1 = __builtin_amdgcn_mfma_f32_16x16x32_f16(ahh1, bh, acc1, 0, 0, 0);
                        acc1 = __builtin_amdgcn_mfma_f32_16x16x32_f16(ahl1, bh, acc1, 0, 0, 0);
                    }
                }
            } else {
                const unsigned short* XHc;
                if constexpr (DEEP)
                    XHc = x_stream + (size_t)t * 65536;
                else
                    XHc = hbuf + ((size_t)((t & 3) * 2 + dir) << 16);

                uint4 vx[16], vh[16];
                if constexpr (DEEP) {
                    #pragma unroll
                    for (int kc = 0; kc < 16; ++kc) {
                        size_t bo = (size_t)ng * 8192 + (size_t)kc * 512 + lofs;
                        vx[kc] = *(const uint4*)(XHc + bo);
                        if (do_hh) vh[kc] = *(const uint4*)(HH + bo);
                    }
                } else {
                    #pragma unroll
                    for (int kc = 0; kc < 16; ++kc) {
                        size_t bo = (size_t)ng * 8192 + (size_t)kc * 512 + lofs;
                        ldg_c(vx[kc], XHc + bo);
                        ldg_c(vh[kc], HH + bo);
                    }
                    vm_drain();
                }
                const bool mv = (t_eff < lenv);
                #pragma unroll
                for (int kc = 0; kc < 16; ++kc) {
                    if (!mv) vx[kc] = make_uint4(0, 0, 0, 0);
                    f16x8 xv = __builtin_bit_cast(f16x8, vx[kc]);
                    const char* ab = smem + kc * 1024 + lane * 16;
                    f16x8 aih0 = *(const f16x8*)(ab);
                    f16x8 aih1 = *(const f16x8*)(ab + 16384);
                    acc0 = __builtin_amdgcn_mfma_f32_16x16x32_f16(aih0, xv, acc0, 0, 0, 0);
                    acc1 = __builtin_amdgcn_mfma_f32_16x16x32_f16(aih1, xv, acc1, 0, 0, 0);
                }
                if (do_hh) {
                    #pragma unroll
                    for (int kc = 0; kc < 16; ++kc) {
                        f16x8 bh = __builtin_bit_cast(f16x8, vh[kc]);
                        const char* ab = smem + kc * 1024 + lane * 16;
                        f16x8 ahh0 = *(const f16x8*)(ab + 65536);
                        f16x8 ahl0 = *(const f16x8*)(ab + 98304);
                        f16x8 ahh1 = *(const f16x8*)(ab + 16384 + 65536);
                        f16x8 ahl1 = *(const f16x8*)(ab + 16384 + 98304);
                        acc0 = __builtin_amdgcn_mfma_f32_16x16x32_f16(ahh0, bh, acc0, 0, 0, 0);
                        acc0 = __builtin_amdgcn_mfma_f32_16x16x32_f16(ahl0, bh, acc0, 0, 0, 0);
                        acc1 = __builtin_amdgcn_mfma_f32_16x16x32_f16(ahh1, bh, acc1, 0, 0, 0);
                        acc1 = __builtin_amdgcn_mfma_f32_16x16x32_f16(ahl1, bh, acc1, 0, 0, 0);
                    }
                }
            }

            // ---- per-wave gate exchange ----
            #pragma unroll
            for (int r = 0; r < 4; ++r) {
                wex[(kg * 4 + r) * 17 + l15]      = acc0[r];
                wex[(16 + kg * 4 + r) * 17 + l15] = acc1[r];
            }
            lds_fence();

            // ---- cell update (coalesced stores) ----
            unsigned short* Hw;
            if constexpr (DEEP)
                Hw = own_stream + (size_t)t * 65536;
            else
                Hw = hbuf + ((size_t)((slot * 4 + p_w) * 2 + dir) << 16);
            unsigned hpk = 0;
            float hm0 = 0.f, hm1 = 0.f;
            #pragma unroll
            for (int j = 0; j < 2; ++j) {
                int u = u0 + j;
                float g0 = wex[(0  + u) * 17 + l15] + bias_l[u];
                float g1 = wex[(8  + u) * 17 + l15] + bias_l[8 + u];
                float g2 = wex[(16 + u) * 17 + l15] + bias_l[16 + u];
                float g3 = wex[(24 + u) * 17 + l15] + bias_l[24 + u];
                float cv = cst[u * 132 + gb];
                float iG = 1.f / (1.f + expf(-g0));
                float fG = 1.f / (1.f + expf(-g1));
                float gG = tanhf(g2);
                float oG = 1.f / (1.f + expf(-g3));
                float cn = fG * cv + iG * gG;
                cst[u * 132 + gb] = cn;
                float hn = oG * tanhf(cn);
                _Float16 hf = (_Float16)hn;
                hpk |= ((unsigned)__builtin_bit_cast(unsigned short, hf)) << (16 * j);
                float hm = (t_eff < lenv) ? hn : 0.f;
                if (j) hm1 = hm; else hm0 = hm;
            }
            stg_c32(Hw + hoff, hpk);
            if (slot) {
                float2 o = make_float2(hm0, hm1);
                *(float2*)(dout + ((size_t)gb * 200 + t_eff) * 1024 + dir * 512 + hj0 + u0) = o;
            }
            vm_drain();
        }

        __syncthreads();
        if (tid == 0)
            __hip_atomic_store(own_f + cu8, (unsigned)(tau + 1),
                               __ATOMIC_RELAXED, __HIP_MEMORY_SCOPE_AGENT);
    }
}

// ---------------- host ----------------
extern "C" void kernel_launch(void* const* d_in, const int* in_sizes, int n_in,
                              void* d_out, int out_size, void* d_ws, size_t ws_size,
                              hipStream_t stream) {
    const float* x     = (const float*)d_in[0];
    const int*   lens  = (const int*)d_in[1];
    const float* Wih_f = (const float*)d_in[2];
    const float* Whh_f = (const float*)d_in[3];
    const float* bih_f = (const float*)d_in[4];
    const float* bhh_f = (const float*)d_in[5];
    const float* Wih_b = (const float*)d_in[6];
    const float* Whh_b = (const float*)d_in[7];
    const float* bih_b = (const float*)d_in[8];
    const float* bhh_b = (const float*)d_in[9];
    float* out = (float*)d_out;
    char* ws = (char*)d_ws;

    const bool deep = (ws_size >= 157321216);
    if (!deep && ws_size < 88114176) return;

    unsigned short* xh    = (unsigned short*)(ws);
    unsigned short* xl    = (unsigned short*)(ws + 26214400);
    unsigned short* wprep = (unsigned short*)(ws + 52428800);
    float* bsum; unsigned short* hbuf; unsigned *flg, *sflg;
    if (deep) {
        hbuf = (unsigned short*)(ws + 52428800);      // hseq, aliases wprep
        bsum = (float*)(ws + 157286400);
        flg  = (unsigned*)(ws + 157319168);
        sflg = (unsigned*)(ws + 157320192);
    } else {
        bsum = (float*)(ws + 85983232);
        hbuf = (unsigned short*)(ws + 86016000);      // quad-buffer
        flg  = (unsigned*)(ws + 88113152);
        sflg = flg;                                   // unused
    }

    prep_x<<<6400, 256, 0, stream>>>(x, xh, xl);
    prep_w<<<1024, 256, 0, stream>>>(Wih_f, wprep, 0, 0);
    prep_w<<<1024, 256, 0, stream>>>(Whh_f, wprep, 0, 1);
    prep_w<<<1024, 256, 0, stream>>>(Wih_b, wprep, 1, 0);
    prep_w<<<1024, 256, 0, stream>>>(Whh_b, wprep, 1, 1);
    bsum_k<<<32, 256, 0, stream>>>(bih_f, bhh_f, bih_b, bhh_b, bsum);
    if (deep)
        reset_k<<<1, 256, 0, stream>>>((uint4*)flg, 128);            // flags + stage flags
    else
        reset_k<<<513, 256, 0, stream>>>((uint4*)hbuf, 131136);      // hbuf + flags

    static const int LDS_BYTES = 131072 + 17408 + 4224 + 128;  // 152,832
    void* k = deep ? reinterpret_cast<void*>(lstm_persist<1>)
                   : reinterpret_cast<void*>(lstm_persist<0>);
    hipFuncSetAttribute(reinterpret_cast<const void*>(k),
                        hipFuncAttributeMaxDynamicSharedMemorySize, LDS_BYTES);

    void* args[] = {(void*)&xh, (void*)&xl, (void*)&wprep, (void*)&bsum,
                    (void*)&hbuf, (void*)&lens, (void*)&out, (void*)&flg, (void*)&sflg};
    hipLaunchCooperativeKernel(k, dim3(256), dim3(512), args, LDS_BYTES, stream);
}

// Round 15
// 1773.597 us; speedup vs baseline: 1.0358x; 1.0358x over previous
//
#include <hip/hip_runtime.h>
#include <hip/hip_bf16.h>

typedef __bf16 bf16x8 __attribute__((ext_vector_type(8)));
typedef _Float16 f16x8 __attribute__((ext_vector_type(8)));
typedef float f32x4 __attribute__((ext_vector_type(4)));

__device__ __forceinline__ unsigned short f2bf(float f) {
    unsigned int u = __builtin_bit_cast(unsigned int, f);
    u += 0x7FFFu + ((u >> 16) & 1u);
    return (unsigned short)(u >> 16);
}
__device__ __forceinline__ float bf2f(unsigned short s) {
    unsigned int u = ((unsigned int)s) << 16;
    return __builtin_bit_cast(float, u);
}

// Coherent (L1/L2-bypass, L3-served) accesses. Loads are issue-only; caller
// batches one s_waitcnt vmcnt(0) + sched_barrier (guide §5.5 rule 18).
__device__ __forceinline__ void ldg_c(uint4& d, const void* p) {
    asm volatile("global_load_dwordx4 %0, %1, off sc0 sc1" : "=v"(d) : "v"(p));
}
__device__ __forceinline__ void stg_c32(void* p, unsigned v) {
    asm volatile("global_store_dword %0, %1, off sc0 sc1" :: "v"(p), "v"(v) : "memory");
}
__device__ __forceinline__ void vm_drain() {
    asm volatile("s_waitcnt vmcnt(0)" ::: "memory");
    __builtin_amdgcn_sched_barrier(0);
}
__device__ __forceinline__ void lds_fence() {
    asm volatile("s_waitcnt lgkmcnt(0)" ::: "memory");
    __builtin_amdgcn_sched_barrier(0);
}

// Wave-parallel flag wait: 64 lanes each watch one CU's flag word.
__device__ __forceinline__ void wait_flags(const unsigned* f, unsigned tgt) {
    int lane = threadIdx.x & 63;
    for (;;) {
        unsigned v = __hip_atomic_load(f + lane, __ATOMIC_RELAXED, __HIP_MEMORY_SCOPE_AGENT);
        if (__all((int)(v >= tgt))) break;
        __builtin_amdgcn_s_sleep(1);
    }
}

// ---------------- prep: x -> split bf16 hi/lo in MFMA B-fragment layout ----------------
// layout: [t(200)][nt(8)][kc(16)][lane(64)][e(8)]; batch = nt*16+(lane&15), k = kc*32+(lane>>4)*8+e
__global__ void prep_x(const float* __restrict__ x,
                       unsigned short* __restrict__ xh,
                       unsigned short* __restrict__ xl) {
    int g = blockIdx.x * 256 + threadIdx.x;   // 1,638,400 frags
    if (g >= 1638400) return;
    int lane = g & 63;
    int kc   = (g >> 6) & 15;
    int nt   = (g >> 10) & 7;
    int t    = g >> 13;
    int batch = nt * 16 + (lane & 15);
    int k = kc * 32 + (lane >> 4) * 8;
    const float* s = x + ((size_t)batch * 200 + t) * 512 + k;
    float4 v0 = *(const float4*)s;
    float4 v1 = *(const float4*)(s + 4);
    float vv[8] = {v0.x, v0.y, v0.z, v0.w, v1.x, v1.y, v1.z, v1.w};
    unsigned int ph[4], pl[4];
    #pragma unroll
    for (int j = 0; j < 4; ++j) {
        float a = vv[2*j], b = vv[2*j+1];
        unsigned short ha = f2bf(a), hb = f2bf(b);
        unsigned short la = f2bf(a - bf2f(ha)), lb = f2bf(b - bf2f(hb));
        ph[j] = (unsigned)ha | ((unsigned)hb << 16);
        pl[j] = (unsigned)la | ((unsigned)lb << 16);
    }
    ((uint4*)xh)[g] = make_uint4(ph[0], ph[1], ph[2], ph[3]);
    ((uint4*)xl)[g] = make_uint4(pl[0], pl[1], pl[2], pl[3]);
}

// ---------------- prep: weights -> per-CU LDS image blocks ----------------
// dst block per (wu = dir*2+layer, cu 0..63): 8192 frags of 16B (131072 B):
//   frag idx within block = mat*2048 + mt*1024 + kc*64 + lane
//   mat: 0=ihH 1=ihL 2=hhH 3=hhL
// Format: layer0 ih = split-bf16 (multiplies x); layer1 ih and all hh = split-fp16.
__global__ void prep_w(const float* __restrict__ W,     // [2][2048][512] f32
                       unsigned short* __restrict__ wprep,
                       int dir, int isHH) {
    int g = blockIdx.x * 256 + threadIdx.x;   // 262,144
    if (g >= 262144) return;
    int lane = g & 63;
    int kc   = (g >> 6) & 15;
    int mt   = (g >> 10) & 1;
    int cu   = (g >> 11) & 63;
    int l    = g >> 17;
    int r = lane & 15;
    int grow = (2 * mt + (r >> 3)) * 512 + cu * 8 + (r & 7);
    int k = kc * 32 + (lane >> 4) * 8;
    const float* s = W + ((size_t)l * 2048 + grow) * 512 + k;
    float4 v0 = *(const float4*)s;
    float4 v1 = *(const float4*)(s + 4);
    float vv[8] = {v0.x, v0.y, v0.z, v0.w, v1.x, v1.y, v1.z, v1.w};
    bool f16fmt = isHH || (l == 1);
    unsigned int ph[4], pl[4];
    #pragma unroll
    for (int j = 0; j < 4; ++j) {
        float a = vv[2*j], b = vv[2*j+1];
        unsigned short ha, hb, la, lb;
        if (f16fmt) {
            _Float16 fa = (_Float16)a, fb = (_Float16)b;
            _Float16 ra = (_Float16)(a - (float)fa), rb = (_Float16)(b - (float)fb);
            ha = __builtin_bit_cast(unsigned short, fa);
            hb = __builtin_bit_cast(unsigned short, fb);
            la = __builtin_bit_cast(unsigned short, ra);
            lb = __builtin_bit_cast(unsigned short, rb);
        } else {
            ha = f2bf(a); hb = f2bf(b);
            la = f2bf(a - bf2f(ha)); lb = f2bf(b - bf2f(hb));
        }
        ph[j] = (unsigned)ha | ((unsigned)hb << 16);
        pl[j] = (unsigned)la | ((unsigned)lb << 16);
    }
    size_t blk = ((size_t)(dir * 2 + l) * 64 + cu) * 8192;
    size_t fH = blk + (size_t)((isHH * 2 + 0) * 2048 + mt * 1024 + kc * 64 + lane);
    size_t fL = blk + (size_t)((isHH * 2 + 1) * 2048 + mt * 1024 + kc * 64 + lane);
    ((uint4*)wprep)[fH] = make_uint4(ph[0], ph[1], ph[2], ph[3]);
    ((uint4*)wprep)[fL] = make_uint4(pl[0], pl[1], pl[2], pl[3]);
}

__global__ void bsum_k(const float* __restrict__ bih_f, const float* __restrict__ bhh_f,
                       const float* __restrict__ bih_b, const float* __restrict__ bhh_b,
                       float* __restrict__ bsum) {
    int i = blockIdx.x * 256 + threadIdx.x;   // 8192 = [dir][l][2048]
    if (i < 8192) {
        int dir = i >> 12, rem = i & 4095;
        const float* bi = dir ? bih_b : bih_f;
        const float* bh = dir ? bhh_b : bhh_f;
        bsum[i] = bi[rem] + bh[rem];
    }
}

__global__ void reset_k(uint4* __restrict__ p) {  // zero hbuf | flags (2,098,176 B)
    int g = blockIdx.x * 256 + threadIdx.x;
    if (g < 131136) p[g] = make_uint4(0, 0, 0, 0);
}

// ---------------- persistent LSTM (cooperative launch, flag-vector barriers) --------
// Measured-best structure (r13 = r10 + verified grafts): per-CU flags, 2 polling
// waves + one s_barrier per step, issue-all-loads + single vmcnt(0) drain,
// coalesced cell update (packed 4B coherent h store, float2 dout, LDS bias),
// slot1 ih = W-hi only. Weights LDS-resident; c in LDS; h = fp16 quad-buffered
// in global via sc0/sc1-coherent accesses (no cache fences needed).
__global__ void __launch_bounds__(512)
lstm_persist(const unsigned short* __restrict__ xh,
             const unsigned short* __restrict__ xl,
             const unsigned short* __restrict__ wprep,
             const float*          __restrict__ bsum,
             unsigned short*       __restrict__ hbuf,   // [(slot*4+parity)*2+dir] x 65536 fp16
             const int*            __restrict__ lens,
             float*                __restrict__ dout,   // [128][200][1024]
             unsigned*             __restrict__ flagv)  // [unit4][cu64]
{
    extern __shared__ char smem[];
    float* wexch  = (float*)(smem + 131072);                  // [ng8][32][17] = 17,408 B
    float* cst    = (float*)(smem + 131072 + 17408);          // [u8][132]    =  4,224 B
    float* bias_l = (float*)(smem + 131072 + 17408 + 4224);   // [q4*8+u]     =    128 B

    const int bid  = blockIdx.x;
    const int xcd  = bid & 7;
    const int unit = xcd >> 1;                        // slot-major: slot*2 + dir
    const int slot = unit >> 1, dir = unit & 1;
    const int cu8  = ((xcd & 1) << 5) | (bid >> 3);   // 0..63
    const int hj0  = cu8 * 8;
    const int tid  = threadIdx.x;
    const int lane = tid & 63, ng = tid >> 6;         // wave = batch group
    const int l15  = lane & 15, kg = lane >> 4;
    const int wsel = dir * 2 + slot;                  // dir-major, matches prep_w/bsum

    const int sib = slot ? dir : (2 + dir);           // other slot, same dir
    unsigned* own_f = flagv + unit * 64;
    unsigned* sib_f = flagv + sib * 64;

    // ---- stage weights into LDS (one-time) ----
    {
        const uint4* src = (const uint4*)wprep + ((size_t)(wsel * 64 + cu8) * 8192);
        uint4* dst = (uint4*)smem;
        #pragma unroll
        for (int i = 0; i < 16; ++i) dst[tid + i * 512] = src[tid + i * 512];
    }
    for (int i = tid; i < 8 * 132; i += 512) cst[i] = 0.f;
    if (tid < 32) bias_l[tid] = bsum[wsel * 2048 + (tid >> 3) * 512 + hj0 + (tid & 7)];
    __syncthreads();

    // ---- loop invariants ----
    const int lenv = lens[ng * 16 + l15];             // len of this lane's batch
    const int gb   = ng * 16 + l15;                   // cell batch for this lane
    const int u0   = kg * 2;                          // cell u-pair for this lane
    const size_t lofs = (size_t)lane * 8;
    const size_t hoff = ((size_t)(ng * 16 + (cu8 >> 2)) * 64 + (cu8 & 3) * 16 + l15) * 8 + u0;
    float* wex = wexch + ng * 32 * 17;

    for (int tau = 0; tau <= 200; ++tau) {
        const int t = slot ? (tau - 1) : tau;
        const bool active = (t >= 0 && t <= 199);
        int t_eff = 0, p_w = 0, p_r = 0;
        if (active) { t_eff = dir ? (199 - t) : t; p_w = t & 3; p_r = (t + 3) & 3; }

        f32x4 acc0 = {0.f, 0.f, 0.f, 0.f};
        f32x4 acc1 = {0.f, 0.f, 0.f, 0.f};

        // ---- Phase 1 (slot0 only): ih * x_t (split-bf16) — recurrence-independent ----
        if (slot == 0 && active) {
            const unsigned short* XH = xh + (size_t)t_eff * 65536;
            const unsigned short* XL = xl + (size_t)t_eff * 65536;
            #pragma unroll
            for (int kc = 0; kc < 16; ++kc) {
                size_t bo = (size_t)ng * 8192 + (size_t)kc * 512 + lofs;
                bf16x8 bxh = *(const bf16x8*)(XH + bo);
                bf16x8 bxl = *(const bf16x8*)(XL + bo);
                const char* ab = smem + kc * 1024 + lane * 16;
                bf16x8 aih0 = *(const bf16x8*)(ab);
                bf16x8 ail0 = *(const bf16x8*)(ab + 32768);
                bf16x8 aih1 = *(const bf16x8*)(ab + 16384);
                bf16x8 ail1 = *(const bf16x8*)(ab + 16384 + 32768);
                acc0 = __builtin_amdgcn_mfma_f32_16x16x32_bf16(aih0, bxh, acc0, 0, 0, 0);
                acc0 = __builtin_amdgcn_mfma_f32_16x16x32_bf16(aih0, bxl, acc0, 0, 0, 0);
                acc0 = __builtin_amdgcn_mfma_f32_16x16x32_bf16(ail0, bxh, acc0, 0, 0, 0);
                acc1 = __builtin_amdgcn_mfma_f32_16x16x32_bf16(aih1, bxh, acc1, 0, 0, 0);
                acc1 = __builtin_amdgcn_mfma_f32_16x16x32_bf16(aih1, bxl, acc1, 0, 0, 0);
                acc1 = __builtin_amdgcn_mfma_f32_16x16x32_bf16(ail1, bxh, acc1, 0, 0, 0);
            }
        }

        // ---- wait for dependencies (parallel wave polls, rest park on s_barrier) ----
        {
            unsigned tgt = (unsigned)tau;
            if (ng == 0) wait_flags(own_f, tgt);                       // own unit done tau-1
            if (slot == 1) { if (ng == 1) wait_flags(sib_f, tgt); }    // data dep
            else if (tau >= 3) { if (ng == 1) wait_flags(sib_f, tgt - 2); }  // WAR (quad-buf)
        }
        __syncthreads();

        if (active) {
            const unsigned short* HH = hbuf + ((size_t)((slot * 4 + p_r) * 2 + dir) << 16);

            // ---- Phase 2: recurrent terms via fp16 h (issue all loads, one drain) ----
            if (slot == 0) {
                uint4 vh[16];
                #pragma unroll
                for (int kc = 0; kc < 16; ++kc)
                    ldg_c(vh[kc], HH + (size_t)ng * 8192 + (size_t)kc * 512 + lofs);
                vm_drain();
                #pragma unroll
                for (int kc = 0; kc < 16; ++kc) {
                    f16x8 bh = __builtin_bit_cast(f16x8, vh[kc]);
                    const char* ab = smem + kc * 1024 + lane * 16;
                    f16x8 ahh0 = *(const f16x8*)(ab + 65536);
                    f16x8 ahl0 = *(const f16x8*)(ab + 98304);
                    f16x8 ahh1 = *(const f16x8*)(ab + 16384 + 65536);
                    f16x8 ahl1 = *(const f16x8*)(ab + 16384 + 98304);
                    acc0 = __builtin_amdgcn_mfma_f32_16x16x32_f16(ahh0, bh, acc0, 0, 0, 0);
                    acc0 = __builtin_amdgcn_mfma_f32_16x16x32_f16(ahl0, bh, acc0, 0, 0, 0);
                    acc1 = __builtin_amdgcn_mfma_f32_16x16x32_f16(ahh1, bh, acc1, 0, 0, 0);
                    acc1 = __builtin_amdgcn_mfma_f32_16x16x32_f16(ahl1, bh, acc1, 0, 0, 0);
                }
            } else {
                int p_x = t & 3;                      // layer0 wrote h_t at parity t&3
                const unsigned short* XHc = hbuf + ((size_t)(p_x * 2 + dir) << 16);
                uint4 vx[16], vh[16];
                #pragma unroll
                for (int kc = 0; kc < 16; ++kc) {
                    size_t bo = (size_t)ng * 8192 + (size_t)kc * 512 + lofs;
                    ldg_c(vx[kc], XHc + bo);
                    ldg_c(vh[kc], HH + bo);
                }
                vm_drain();
                const bool mv = (t_eff < lenv);
                #pragma unroll
                for (int kc = 0; kc < 16; ++kc) {
                    if (!mv) vx[kc] = make_uint4(0, 0, 0, 0);
                    f16x8 xv = __builtin_bit_cast(f16x8, vx[kc]);
                    f16x8 bh = __builtin_bit_cast(f16x8, vh[kc]);
                    const char* ab = smem + kc * 1024 + lane * 16;
                    f16x8 aih0 = *(const f16x8*)(ab);
                    f16x8 ahh0 = *(const f16x8*)(ab + 65536);
                    f16x8 ahl0 = *(const f16x8*)(ab + 98304);
                    f16x8 aih1 = *(const f16x8*)(ab + 16384);
                    f16x8 ahh1 = *(const f16x8*)(ab + 16384 + 65536);
                    f16x8 ahl1 = *(const f16x8*)(ab + 16384 + 98304);
                    acc0 = __builtin_amdgcn_mfma_f32_16x16x32_f16(aih0, xv, acc0, 0, 0, 0);
                    acc0 = __builtin_amdgcn_mfma_f32_16x16x32_f16(ahh0, bh, acc0, 0, 0, 0);
                    acc0 = __builtin_amdgcn_mfma_f32_16x16x32_f16(ahl0, bh, acc0, 0, 0, 0);
                    acc1 = __builtin_amdgcn_mfma_f32_16x16x32_f16(aih1, xv, acc1, 0, 0, 0);
                    acc1 = __builtin_amdgcn_mfma_f32_16x16x32_f16(ahh1, bh, acc1, 0, 0, 0);
                    acc1 = __builtin_amdgcn_mfma_f32_16x16x32_f16(ahl1, bh, acc1, 0, 0, 0);
                }
            }

            // ---- per-wave gate exchange (private LDS region) ----
            #pragma unroll
            for (int r = 0; r < 4; ++r) {
                wex[(kg * 4 + r) * 17 + l15]      = acc0[r];
                wex[(16 + kg * 4 + r) * 17 + l15] = acc1[r];
            }
            lds_fence();   // intra-wave write->read ordering

            // ---- cell update: lane = (batch l15, u-pair u0); coalesced stores ----
            unsigned short* Hw = hbuf + ((size_t)((slot * 4 + p_w) * 2 + dir) << 16);
            unsigned hpk = 0;
            float hm0 = 0.f, hm1 = 0.f;
            #pragma unroll
            for (int j = 0; j < 2; ++j) {
                int u = u0 + j;
                float g0 = wex[(0  + u) * 17 + l15] + bias_l[u];
                float g1 = wex[(8  + u) * 17 + l15] + bias_l[8 + u];
                float g2 = wex[(16 + u) * 17 + l15] + bias_l[16 + u];
                float g3 = wex[(24 + u) * 17 + l15] + bias_l[24 + u];
                float cv = cst[u * 132 + gb];
                float iG = 1.f / (1.f + expf(-g0));
                float fG = 1.f / (1.f + expf(-g1));
                float gG = tanhf(g2);
                float oG = 1.f / (1.f + expf(-g3));
                float cn = fG * cv + iG * gG;
                cst[u * 132 + gb] = cn;
                float hn = oG * tanhf(cn);
                _Float16 hf = (_Float16)hn;
                hpk |= ((unsigned)__builtin_bit_cast(unsigned short, hf)) << (16 * j);
                float hm = (t_eff < lenv) ? hn : 0.f;
                if (j) hm1 = hm; else hm0 = hm;
            }
            stg_c32(Hw + hoff, hpk);
            if (slot) {
                float2 o = make_float2(hm0, hm1);
                *(float2*)(dout + ((size_t)gb * 200 + t_eff) * 1024 + dir * 512 + hj0 + u0) = o;
            }
            vm_drain();    // coherent h stores drained before the signal
        }

        __syncthreads();
        if (tid == 0)
            __hip_atomic_store(own_f + cu8, (unsigned)(tau + 1),
                               __ATOMIC_RELAXED, __HIP_MEMORY_SCOPE_AGENT);
    }
}

// ---------------- host ----------------
extern "C" void kernel_launch(void* const* d_in, const int* in_sizes, int n_in,
                              void* d_out, int out_size, void* d_ws, size_t ws_size,
                              hipStream_t stream) {
    const float* x     = (const float*)d_in[0];
    const int*   lens  = (const int*)d_in[1];     // int32 (JAX x64-disabled)
    const float* Wih_f = (const float*)d_in[2];
    const float* Whh_f = (const float*)d_in[3];
    const float* bih_f = (const float*)d_in[4];
    const float* bhh_f = (const float*)d_in[5];
    const float* Wih_b = (const float*)d_in[6];
    const float* Whh_b = (const float*)d_in[7];
    const float* bih_b = (const float*)d_in[8];
    const float* bhh_b = (const float*)d_in[9];
    float* out = (float*)d_out;
    char* ws = (char*)d_ws;
    if (ws_size < 88114176) return;

    unsigned short* xh    = (unsigned short*)(ws);                 // 26,214,400
    unsigned short* xl    = (unsigned short*)(ws + 26214400);      // 26,214,400
    unsigned short* wprep = (unsigned short*)(ws + 52428800);      // 33,554,432
    float*          bsum  = (float*)(ws + 85983232);               //     32,768
    unsigned short* hbuf  = (unsigned short*)(ws + 86016000);      //  2,097,152 (16 x 128KB)
    unsigned*       flg   = (unsigned*)(ws + 88113152);            //      1,024

    prep_x<<<6400, 256, 0, stream>>>(x, xh, xl);
    prep_w<<<1024, 256, 0, stream>>>(Wih_f, wprep, 0, 0);
    prep_w<<<1024, 256, 0, stream>>>(Whh_f, wprep, 0, 1);
    prep_w<<<1024, 256, 0, stream>>>(Wih_b, wprep, 1, 0);
    prep_w<<<1024, 256, 0, stream>>>(Whh_b, wprep, 1, 1);
    bsum_k<<<32, 256, 0, stream>>>(bih_f, bhh_f, bih_b, bhh_b, bsum);
    reset_k<<<513, 256, 0, stream>>>((uint4*)hbuf);   // zeroes hbuf | flags (contiguous)

    static const int LDS_BYTES = 131072 + 17408 + 4224 + 128;  // 152,832
    hipFuncSetAttribute(reinterpret_cast<const void*>(lstm_persist),
                        hipFuncAttributeMaxDynamicSharedMemorySize, LDS_BYTES);

    void* args[] = {(void*)&xh, (void*)&xl, (void*)&wprep, (void*)&bsum,
                    (void*)&hbuf, (void*)&lens, (void*)&out, (void*)&flg};
    hipLaunchCooperativeKernel(reinterpret_cast<void*>(lstm_persist),
                               dim3(256), dim3(512), args, LDS_BYTES, stream);
}